// Round 8
// baseline (138.282 us; speedup 1.0000x reference)
//
#include <hip/hip_runtime.h>

// ---------------------------------------------------------------------------
// STRODE fused kernel for MI355X (gfx950) — round 7 (resubmit; infra flake)
//
// = round 5's P/Q stage-skew pipeline (two independent 16-row blocks per WG,
//   skewed by one stage so every phase runs two independent chains)
// + round 6's amdgpu_waves_per_eu(2,2) (exact 2 waves/SIMD -> 256-reg unified
//   VGPR/AGPR budget; r5's 137us was this same structure SPILLED at 128).
//
// Per wave w (0..7), 256 WGs x 512 thr, 32 rows/WG:
//   S1: H1[16b][u-tile w] = tanh(W1 Y^T + b1)    A=w1r regs (64)
//   S2: H2[16b][u'-tile w] = tanh(H1 W2^T+b2)*dt B=w2r regs (16)
//   S3: Y[16b] += W3 H2^T + b3*dt                A=w3r regs (64), acc in Yr
// Schedule: S1(P); { A: S2(P)+S1(Q) | B: S3(P)+S2(Q) | C: S1(P,s+1)+S3(Q) }
// ---------------------------------------------------------------------------

typedef __attribute__((ext_vector_type(8))) short s16x8;   // 8 x bf16 frag
typedef __attribute__((ext_vector_type(4))) float fx4;     // MFMA acc

#define NB   8192
#define DD   512
#define UU   100
#define UP   128

__device__ __forceinline__ unsigned int f2bf(float x) {
  unsigned int u = __float_as_uint(x);
  return (u + 0x7FFFu + ((u >> 16) & 1u)) >> 16;   // RNE, no NaN inputs
}
__device__ __forceinline__ float bf2f(unsigned int h) {
  return __uint_as_float(h << 16);
}
__device__ __forceinline__ float tanh_fast(float x) {
  float e = __expf(2.0f * x);
  return 1.0f - 2.0f / (e + 1.0f);
}

// ---------------------------------------------------------------------------
// Weight prep: fp32 -> bf16, pad U=100 -> 128 with zeros.
// ---------------------------------------------------------------------------
__global__ void prep_weights(const float* __restrict__ W1,
                             const float* __restrict__ W2,
                             const float* __restrict__ W3,
                             unsigned short* __restrict__ ws) {
  int e = blockIdx.x * 256 + threadIdx.x;
  if (e < 65536) {
    int u = e >> 9, kc = e & 511;
    ws[e] = (u < UU) ? (unsigned short)f2bf(W1[u * DD + kc]) : (unsigned short)0;
  } else if (e < 81920) {
    int e2 = e - 65536;
    int n = e2 >> 7, kc = e2 & 127;
    ws[e] = (n < UU && kc < UU) ? (unsigned short)f2bf(W2[n * UU + kc]) : (unsigned short)0;
  } else if (e < 147456) {
    int e3 = e - 81920;
    int d = e3 >> 7, kc = e3 & 127;
    ws[e] = (kc < UU) ? (unsigned short)f2bf(W3[d * UU + kc]) : (unsigned short)0;
  }
}

// ---------------------------------------------------------------------------
// Main fused ODE kernel. grid = 256 WGs x 512 thr (8 waves), 32 rows/WG.
// ---------------------------------------------------------------------------
__global__ __launch_bounds__(512) __attribute__((amdgpu_waves_per_eu(2, 2)))
void ode_main(
    const float* __restrict__ y0, const float* __restrict__ t_seq,
    const float* __restrict__ b1, const float* __restrict__ b2,
    const float* __restrict__ b3,
    const unsigned short* __restrict__ W1b,
    const unsigned short* __restrict__ W2b,
    const unsigned short* __restrict__ W3b,
    const int* __restrict__ kptr, float* __restrict__ out) {
  __shared__ char YbP[16 * DD * 2], YbQ[16 * DD * 2];   // 16 KB each
  __shared__ char H1P[16 * UP * 2], H1Q[16 * UP * 2];   //  4 KB each
  __shared__ char H2P[16 * UP * 2], H2Q[16 * UP * 2];   //  4 KB each

  const int tid  = threadIdx.x;
  const int w    = tid >> 6;          // wave 0..7
  const int lane = tid & 63;
  const int lo   = lane & 15;
  const int hi   = lane >> 4;
  const int swl  = (lo & 7) << 4;     // swizzle when row == lo
  const int b0   = blockIdx.x * 32;   // block P rows; Q = b0+16
  const int k    = *kptr;
  const float kinv = 1.0f / (float)k;

  // ---- register-resident weights ----------------------------------------
  s16x8 w1r[16];                      // W1[u=16w+lo][K=512]  64 regs
#pragma unroll
  for (int kk = 0; kk < 16; ++kk)
    w1r[kk] = *(const s16x8*)(W1b + (16 * w + lo) * DD + kk * 32 + hi * 8);
  s16x8 w2r[4];                       // W2[u'=16w+lo][K=128] 16 regs
#pragma unroll
  for (int kk = 0; kk < 4; ++kk)
    w2r[kk] = *(const s16x8*)(W2b + (16 * w + lo) * UP + kk * 32 + hi * 8);
  s16x8 w3r[4][4];                    // W3[d=(4w+i)*16+lo][K=128] 64 regs
#pragma unroll
  for (int i = 0; i < 4; ++i)
#pragma unroll
    for (int kk = 0; kk < 4; ++kk)
      w3r[i][kk] = *(const s16x8*)(W3b + ((4 * w + i) * 16 + lo) * UP + kk * 32 + hi * 8);

  // ---- hoisted per-thread constants -------------------------------------
  float b1v[4];                       // u = 16w + 4hi + r
#pragma unroll
  for (int r = 0; r < 4; ++r) {
    int u = 16 * w + 4 * hi + r;
    b1v[r] = (u < UU) ? b1[u] : 0.0f;
  }
  float b2v;                          // u' = 16w + lo
  { int u = 16 * w + lo; b2v = (u < UU) ? b2[u] : 0.0f; }
  float b3v[4][4];                    // d = (4w+i)*16 + 4hi + r
#pragma unroll
  for (int i = 0; i < 4; ++i)
#pragma unroll
    for (int r = 0; r < 4; ++r)
      b3v[i][r] = b3[(4 * w + i) * 16 + 4 * hi + r];

  float dt2P[4], dt2Q[4];             // stage2 rows: b_local = 4hi + r
#pragma unroll
  for (int r = 0; r < 4; ++r) {
    int bp = b0 + 4 * hi + r, bq = bp + 16;
    dt2P[r] = (t_seq[2 * bp + 1] - t_seq[2 * bp]) * kinv;
    dt2Q[r] = (t_seq[2 * bq + 1] - t_seq[2 * bq]) * kinv;
  }
  float dt3P, dt3Q;                   // stage1/3 cols: b_local = lo
  {
    int bp = b0 + lo, bq = bp + 16;
    dt3P = (t_seq[2 * bp + 1] - t_seq[2 * bp]) * kinv;
    dt3Q = (t_seq[2 * bq + 1] - t_seq[2 * bq]) * kinv;
  }

  // ---- persistent Y in registers (stage-3 D layout) ---------------------
  // Yr[i][r] = Y[b = lo][d = (4w+i)*16 + 4hi + r]
  fx4 YrP[4], YrQ[4];
#pragma unroll
  for (int i = 0; i < 4; ++i) {
    const float* pp = y0 + (size_t)(b0 + lo) * DD + (4 * w + i) * 16 + 4 * hi;
    YrP[i] = *(const fx4*)pp;
    YrQ[i] = *(const fx4*)(pp + 16 * DD);
  }

  auto wYb = [&](char* Yb, fx4* Yr) {
#pragma unroll
    for (int i = 0; i < 4; ++i) {
      uint2 q;
      q.x = f2bf(Yr[i][0]) | (f2bf(Yr[i][1]) << 16);
      q.y = f2bf(Yr[i][2]) | (f2bf(Yr[i][3]) << 16);
      *(uint2*)(Yb + lo * 1024 + ((128 * w + 32 * i + 8 * hi) ^ swl)) = q;
    }
  };

  const fx4 zf = {0.f, 0.f, 0.f, 0.f};

  // ---- stage bodies ------------------------------------------------------
  auto S1 = [&](const char* Yb, char* H1) {    // H1 = tanh(W1 Y^T + b1)
    fx4 a0 = zf, a1 = zf;
#pragma unroll
    for (int kk = 0; kk < 16; kk += 2) {
      s16x8 bb0 = *(const s16x8*)(Yb + lo * 1024 + ((kk * 64 + hi * 16) ^ swl));
      s16x8 bb1 = *(const s16x8*)(Yb + lo * 1024 + (((kk + 1) * 64 + hi * 16) ^ swl));
      a0 = __builtin_amdgcn_mfma_f32_16x16x32_bf16(w1r[kk], bb0, a0, 0, 0, 0);
      a1 = __builtin_amdgcn_mfma_f32_16x16x32_bf16(w1r[kk + 1], bb1, a1, 0, 0, 0);
    }
    uint2 q;
    q.x = f2bf(tanh_fast(a0[0] + a1[0] + b1v[0])) |
          (f2bf(tanh_fast(a0[1] + a1[1] + b1v[1])) << 16);
    q.y = f2bf(tanh_fast(a0[2] + a1[2] + b1v[2])) |
          (f2bf(tanh_fast(a0[3] + a1[3] + b1v[3])) << 16);
    *(uint2*)(H1 + lo * 256 + ((32 * w + 8 * hi) ^ swl)) = q;
  };

  auto S2 = [&](const char* H1, char* H2, const float* dt2) {  // H2 = tanh(H1 W2^T+b2)*dt
    fx4 a0 = zf, a1 = zf;
#pragma unroll
    for (int kk = 0; kk < 4; kk += 2) {
      s16x8 m0 = *(const s16x8*)(H1 + lo * 256 + ((kk * 64 + hi * 16) ^ swl));
      s16x8 m1 = *(const s16x8*)(H1 + lo * 256 + (((kk + 1) * 64 + hi * 16) ^ swl));
      a0 = __builtin_amdgcn_mfma_f32_16x16x32_bf16(m0, w2r[kk], a0, 0, 0, 0);
      a1 = __builtin_amdgcn_mfma_f32_16x16x32_bf16(m1, w2r[kk + 1], a1, 0, 0, 0);
    }
#pragma unroll
    for (int r = 0; r < 4; ++r) {
      int row = 4 * hi + r;
      float hv = tanh_fast(a0[r] + a1[r] + b2v) * dt2[r];
      *(unsigned short*)(H2 + row * 256 + ((32 * w + 2 * lo) ^ ((row & 7) << 4))) =
          (unsigned short)f2bf(hv);
    }
  };

  auto S3 = [&](const char* H2, char* Yb, fx4* Yr, float dt3x) {  // Y += W3 H2^T + b3*dt
#pragma unroll
    for (int kk = 0; kk < 4; ++kk) {
      s16x8 bb = *(const s16x8*)(H2 + lo * 256 + ((kk * 64 + hi * 16) ^ swl));
#pragma unroll
      for (int i = 0; i < 4; ++i)
        Yr[i] = __builtin_amdgcn_mfma_f32_16x16x32_bf16(w3r[i][kk], bb, Yr[i], 0, 0, 0);
    }
#pragma unroll
    for (int i = 0; i < 4; ++i)
#pragma unroll
      for (int r = 0; r < 4; ++r) Yr[i][r] += b3v[i][r] * dt3x;
    wYb(Yb, Yr);
  };

  // ---- pipeline: prologue + 3 skewed phases per step --------------------
  wYb(YbP, YrP);
  wYb(YbQ, YrQ);
  __syncthreads();
  S1(YbP, H1P);
  __syncthreads();

#pragma unroll 1
  for (int s = 0; s < k; ++s) {
    // phase A: S2(P) || S1(Q)
    S2(H1P, H2P, dt2P);
    S1(YbQ, H1Q);
    __syncthreads();
    // phase B: S3(P) || S2(Q)
    S3(H2P, YbP, YrP, dt3P);
    S2(H1Q, H2Q, dt2Q);
    __syncthreads();
    // phase C: S1(P,s+1) || S3(Q)
    if (s + 1 < k) S1(YbP, H1P);
    S3(H2Q, YbQ, YrQ, dt3Q);
    __syncthreads();
  }

  // ---- final store: coalesced fp32 from bf16 Yb -------------------------
  for (int idx = tid; idx < 32 * DD; idx += 512) {
    int b = idx >> 9, d = idx & 511;
    const char* src = (b < 16) ? YbP : YbQ;
    int row = b & 15;
    unsigned short h =
        *(const unsigned short*)(src + row * 1024 + ((2 * d) ^ ((row & 7) << 4)));
    out[(size_t)(b0 + b) * 513 + d] = bf2f((unsigned int)h);
  }
}

// ---------------------------------------------------------------------------
// Loss column:  loss = ycum[-2] = 0.01 * sum_{t=1..98} gm_t   (exact algebra)
// ---------------------------------------------------------------------------
__global__ void loss_kernel(const float* __restrict__ bdp,
                            const float* __restrict__ sp,
                            const float* __restrict__ sdp,
                            float* __restrict__ out) {
  int b = blockIdx.x * 256 + threadIdx.x;
  if (b >= NB) return;
  float bd = bdp[b];
  float Kv = sp[b] + __logf(-bd + 0.01f) - __logf(sdp[b] + 0.01f);
  float acc = 0.0f;
  for (int t = 1; t <= 98; ++t) {
    float m = 0.01f * (float)t - 1.0f;     // in (-1, 0)
    float L = __logf(-m);                  // negative
    acc += (-bd) / (m * L) * (Kv - __logf(-L));
  }
  out[(size_t)b * 513 + 512] = 0.01f * acc;
}

// ---------------------------------------------------------------------------
extern "C" void kernel_launch(void* const* d_in, const int* in_sizes, int n_in,
                              void* d_out, int out_size, void* d_ws, size_t ws_size,
                              hipStream_t stream) {
  const float* y0    = (const float*)d_in[0];
  const float* t_seq = (const float*)d_in[1];
  const float* W1    = (const float*)d_in[2];
  const float* b1    = (const float*)d_in[3];
  const float* W2    = (const float*)d_in[4];
  const float* b2    = (const float*)d_in[5];
  const float* W3    = (const float*)d_in[6];
  const float* b3    = (const float*)d_in[7];
  const float* bd    = (const float*)d_in[9];
  const float* s_    = (const float*)d_in[10];
  const float* sd    = (const float*)d_in[11];
  const int*   kptr  = (const int*)d_in[12];
  float* out = (float*)d_out;
  unsigned short* ws = (unsigned short*)d_ws;

  prep_weights<<<576, 256, 0, stream>>>(W1, W2, W3, ws);
  ode_main<<<256, 512, 0, stream>>>(y0, t_seq, b1, b2, b3,
                                    ws, ws + 65536, ws + 81920, kptr, out);
  loss_kernel<<<32, 256, 0, stream>>>(bd, s_, sd, out);
}

// Round 9
// 102.256 us; speedup vs baseline: 1.3523x; 1.3523x over previous
//
#include <hip/hip_runtime.h>

// ---------------------------------------------------------------------------
// STRODE fused kernel for MI355X (gfx950) — round 9
// r6 base (101 us, best) + VALU-diet:
//   * v_cvt_pk_bf16_f32 packing (1 instr / 2 values, was ~3/value)
//   * tanh = 1 - 2/(exp2(2log2e*x)+1)  (5 VALU, was ~7)
//   * S1 split into 4 accumulator chains (8-deep, was 16-deep)
//   * s_setprio(1) around MFMA clusters
// Rationale: VALU-busy ~43-48 us invariant across ALL rounds (structure-
// independent) and step time ~= VALU+LDS+MFMA serially summed -> cut the
// largest serial term. Discriminator: if VALUBusy doesn't drop, the
// inflation is compiler reg-shuffling, not source arithmetic.
// ---------------------------------------------------------------------------

typedef __attribute__((ext_vector_type(8))) short s16x8;   // 8 x bf16 frag
typedef __attribute__((ext_vector_type(4))) float fx4;     // MFMA acc

#define NB   8192
#define DD   512
#define UU   100
#define UP   128
#define BM   32

__device__ __forceinline__ unsigned int f2bf(float x) {
  unsigned int u = __float_as_uint(x);
  return (u + 0x7FFFu + ((u >> 16) & 1u)) >> 16;   // RNE (prep kernel only)
}
__device__ __forceinline__ float bf2f(unsigned int h) {
  return __uint_as_float(h << 16);
}
__device__ __forceinline__ unsigned int cvt_pk_bf16(float lo, float hi) {
  unsigned int r;
  asm("v_cvt_pk_bf16_f32 %0, %1, %2" : "=v"(r) : "v"(lo), "v"(hi));
  return r;                                         // low16=bf16(lo), high16=bf16(hi)
}
__device__ __forceinline__ float tanh5(float x) {
  // tanh(x) = 1 - 2/(2^(x*2*log2e)+1); exact limits at +/-inf, no NaN.
  float e = __builtin_amdgcn_exp2f(x * 2.885390081777927f);
  return 1.0f - 2.0f / (e + 1.0f);
}

// ---------------------------------------------------------------------------
// Weight prep: fp32 -> bf16, pad U=100 -> 128 with zeros.
// ---------------------------------------------------------------------------
__global__ void prep_weights(const float* __restrict__ W1,
                             const float* __restrict__ W2,
                             const float* __restrict__ W3,
                             unsigned short* __restrict__ ws) {
  int e = blockIdx.x * 256 + threadIdx.x;
  if (e < 65536) {
    int u = e >> 9, kc = e & 511;
    ws[e] = (u < UU) ? (unsigned short)f2bf(W1[u * DD + kc]) : (unsigned short)0;
  } else if (e < 81920) {
    int e2 = e - 65536;
    int n = e2 >> 7, kc = e2 & 127;
    ws[e] = (n < UU && kc < UU) ? (unsigned short)f2bf(W2[n * UU + kc]) : (unsigned short)0;
  } else if (e < 147456) {
    int e3 = e - 81920;
    int d = e3 >> 7, kc = e3 & 127;
    ws[e] = (kc < UU) ? (unsigned short)f2bf(W3[d * UU + kc]) : (unsigned short)0;
  }
}

// ---------------------------------------------------------------------------
// Main fused ODE kernel. grid = 256 WGs x 512 thr (8 waves), 32 rows/WG.
// ---------------------------------------------------------------------------
__global__ __launch_bounds__(512) __attribute__((amdgpu_waves_per_eu(2, 2)))
void ode_main(
    const float* __restrict__ y0, const float* __restrict__ t_seq,
    const float* __restrict__ b1, const float* __restrict__ b2,
    const float* __restrict__ b3,
    const unsigned short* __restrict__ W1b,
    const unsigned short* __restrict__ W2b,
    const unsigned short* __restrict__ W3b,
    const int* __restrict__ kptr, float* __restrict__ out) {
  __shared__ char Yb[BM * DD * 2];    // 32 KB bf16 Y [32][512], swizzled
  __shared__ char H1s[BM * UP * 2];   //  8 KB bf16 H1 [32][128], swizzled
  __shared__ char H2s[BM * UP * 2];   //  8 KB bf16 H2*dt [32][128], swizzled
  __shared__ char W2s[UP * UP * 2];   // 32 KB bf16 W2 [128][128], swizzled

  const int tid  = threadIdx.x;
  const int w    = tid >> 6;          // wave 0..7
  const int lane = tid & 63;
  const int lo   = lane & 15;
  const int hi   = lane >> 4;
  const int m2   = w >> 2;            // stage2 batch half
  const int n0   = 2 * (w & 3);       // stage2 first n-tile
  const int b0   = blockIdx.x * BM;
  const int k    = *kptr;
  const float kinv = 1.0f / (float)k;

  auto yboff = [](int b, int byr) -> int { return (b << 10) + (byr ^ ((b & 7) << 4)); };
  auto hoff  = [](int r, int byr) -> int { return (r << 8)  + (byr ^ ((r & 7) << 4)); };

  // ---- register-resident weights ----------------------------------------
  s16x8 w1r[16];                      // W1[u=16w+lo][K=512]   64 regs
#pragma unroll
  for (int kk = 0; kk < 16; ++kk)
    w1r[kk] = *(const s16x8*)(W1b + (16 * w + lo) * DD + kk * 32 + hi * 8);
  s16x8 w3r[4][4];                    // W3[d=(4w+i)*16+lo][K=128]  64 regs
#pragma unroll
  for (int i = 0; i < 4; ++i)
#pragma unroll
    for (int kk = 0; kk < 4; ++kk)
      w3r[i][kk] = *(const s16x8*)(W3b + ((4 * w + i) * 16 + lo) * UP + kk * 32 + hi * 8);

  // ---- stage W2 into LDS once (swizzled, 16B granules) ------------------
  for (int g = tid; g < 2048; g += 512) {
    int n = g >> 4, c8 = g & 15;
    uint4 v = *(const uint4*)(W2b + n * UP + c8 * 8);
    *(uint4*)(W2s + (n << 8) + ((c8 * 16) ^ ((n & 7) << 4))) = v;
  }

  // ---- hoisted per-thread constants -------------------------------------
  float b1v[4];                       // u = 16w + 4hi + r
#pragma unroll
  for (int r = 0; r < 4; ++r) {
    int u = 16 * w + 4 * hi + r;
    b1v[r] = (u < UU) ? b1[u] : 0.0f;
  }
  float b2v[2];                       // u' = (n0+nj)*16 + lo
#pragma unroll
  for (int nj = 0; nj < 2; ++nj) {
    int u = (n0 + nj) * 16 + lo;
    b2v[nj] = (u < UU) ? b2[u] : 0.0f;
  }
  float dtrow[4];                     // stage2 rows: b = m2*16 + 4hi + r
#pragma unroll
  for (int r = 0; r < 4; ++r) {
    int b = b0 + m2 * 16 + 4 * hi + r;
    dtrow[r] = (t_seq[2 * b + 1] - t_seq[2 * b]) * kinv;
  }
  float dt3[2];                       // stage3 cols: b = j*16 + lo
#pragma unroll
  for (int j = 0; j < 2; ++j) {
    int b = b0 + j * 16 + lo;
    dt3[j] = (t_seq[2 * b + 1] - t_seq[2 * b]) * kinv;
  }
  float b3v[4][4];                    // d = (4w+i)*16 + 4hi + r
#pragma unroll
  for (int i = 0; i < 4; ++i)
#pragma unroll
    for (int r = 0; r < 4; ++r)
      b3v[i][r] = b3[(4 * w + i) * 16 + 4 * hi + r];

  // ---- persistent Y in registers (stage-3 D layout), 32 regs ------------
  // Yr[i][j][r] = Y[b = j*16+lo][d = (4w+i)*16 + 4hi + r]
  fx4 Yr[4][2];
#pragma unroll
  for (int i = 0; i < 4; ++i)
#pragma unroll
    for (int j = 0; j < 2; ++j) {
      const float* p = y0 + (size_t)(b0 + j * 16 + lo) * DD + (4 * w + i) * 16 + 4 * hi;
      Yr[i][j] = *(const fx4*)p;
    }

  auto write_yb = [&]() {
#pragma unroll
    for (int i = 0; i < 4; ++i)
#pragma unroll
      for (int j = 0; j < 2; ++j) {
        int b   = j * 16 + lo;
        int byr = ((4 * w + i) * 16 + 4 * hi) * 2;
        uint2 q;
        q.x = cvt_pk_bf16(Yr[i][j][0], Yr[i][j][1]);
        q.y = cvt_pk_bf16(Yr[i][j][2], Yr[i][j][3]);
        *(uint2*)(Yb + yboff(b, byr)) = q;
      }
  };
  write_yb();
  __syncthreads();

  const fx4 zf = {0.f, 0.f, 0.f, 0.f};

#pragma unroll 1
  for (int s = 0; s < k; ++s) {
    // ===== S1: H1^T[u-tile w][32b] = tanh(W1 Y^T + b1) ===================
    // 4 accumulator chains (8-deep) instead of 2 (16-deep).
    fx4 aA[2], aB[2];
    aA[0] = zf; aA[1] = zf; aB[0] = zf; aB[1] = zf;
    __builtin_amdgcn_s_setprio(1);
#pragma unroll
    for (int kk = 0; kk < 16; kk += 2) {
      int bro0 = kk * 64 + hi * 16;
      int bro1 = (kk + 1) * 64 + hi * 16;
      s16x8 b00 = *(const s16x8*)(Yb + yboff(lo, bro0));
      s16x8 b01 = *(const s16x8*)(Yb + yboff(16 + lo, bro0));
      s16x8 b10 = *(const s16x8*)(Yb + yboff(lo, bro1));
      s16x8 b11 = *(const s16x8*)(Yb + yboff(16 + lo, bro1));
      aA[0] = __builtin_amdgcn_mfma_f32_16x16x32_bf16(w1r[kk], b00, aA[0], 0, 0, 0);
      aA[1] = __builtin_amdgcn_mfma_f32_16x16x32_bf16(w1r[kk], b01, aA[1], 0, 0, 0);
      aB[0] = __builtin_amdgcn_mfma_f32_16x16x32_bf16(w1r[kk + 1], b10, aB[0], 0, 0, 0);
      aB[1] = __builtin_amdgcn_mfma_f32_16x16x32_bf16(w1r[kk + 1], b11, aB[1], 0, 0, 0);
    }
    __builtin_amdgcn_s_setprio(0);
#pragma unroll
    for (int j = 0; j < 2; ++j) {
      int b   = j * 16 + lo;
      int byr = (16 * w + 4 * hi) * 2;
      float v0 = aA[j][0] + aB[j][0] + b1v[0];
      float v1 = aA[j][1] + aB[j][1] + b1v[1];
      float v2 = aA[j][2] + aB[j][2] + b1v[2];
      float v3 = aA[j][3] + aB[j][3] + b1v[3];
      uint2 q;
      q.x = cvt_pk_bf16(tanh5(v0), tanh5(v1));
      q.y = cvt_pk_bf16(tanh5(v2), tanh5(v3));
      *(uint2*)(H1s + hoff(b, byr)) = q;
    }
    __syncthreads();

    // ===== S2: H2[m2][n0,n0+1] = tanh(H1 W2^T + b2) * dt =================
    fx4 acc2[2];
    acc2[0] = zf; acc2[1] = zf;
    __builtin_amdgcn_s_setprio(1);
#pragma unroll
    for (int kk = 0; kk < 4; ++kk) {
      int bro = kk * 64 + hi * 16;
      s16x8 am  = *(const s16x8*)(H1s + hoff(m2 * 16 + lo, bro));
      s16x8 wb0 = *(const s16x8*)(W2s + hoff((n0 + 0) * 16 + lo, bro));
      s16x8 wb1 = *(const s16x8*)(W2s + hoff((n0 + 1) * 16 + lo, bro));
      acc2[0] = __builtin_amdgcn_mfma_f32_16x16x32_bf16(am, wb0, acc2[0], 0, 0, 0);
      acc2[1] = __builtin_amdgcn_mfma_f32_16x16x32_bf16(am, wb1, acc2[1], 0, 0, 0);
    }
    __builtin_amdgcn_s_setprio(0);
#pragma unroll
    for (int nj = 0; nj < 2; ++nj) {
      int byr = ((n0 + nj) * 16 + lo) * 2;
#pragma unroll
      for (int r = 0; r < 4; ++r) {
        int b = m2 * 16 + 4 * hi + r;
        float hv = tanh5(acc2[nj][r] + b2v[nj]) * dtrow[r];
        unsigned int pk = cvt_pk_bf16(hv, hv);
        *(unsigned short*)(H2s + hoff(b, byr)) = (unsigned short)pk;
      }
    }
    __syncthreads();

    // ===== S3: Y += W3 H2'^T + b3*dt  (acc straight into Yr) =============
    __builtin_amdgcn_s_setprio(1);
#pragma unroll
    for (int kk = 0; kk < 4; ++kk) {
      int bro = kk * 64 + hi * 16;
      s16x8 bb0 = *(const s16x8*)(H2s + hoff(lo, bro));
      s16x8 bb1 = *(const s16x8*)(H2s + hoff(16 + lo, bro));
#pragma unroll
      for (int i = 0; i < 4; ++i) {
        Yr[i][0] = __builtin_amdgcn_mfma_f32_16x16x32_bf16(w3r[i][kk], bb0, Yr[i][0], 0, 0, 0);
        Yr[i][1] = __builtin_amdgcn_mfma_f32_16x16x32_bf16(w3r[i][kk], bb1, Yr[i][1], 0, 0, 0);
      }
    }
    __builtin_amdgcn_s_setprio(0);
#pragma unroll
    for (int i = 0; i < 4; ++i)
#pragma unroll
      for (int j = 0; j < 2; ++j)
#pragma unroll
        for (int r = 0; r < 4; ++r) Yr[i][j][r] += b3v[i][r] * dt3[j];

    write_yb();
    __syncthreads();
  }

  // ---- final store: coalesced fp32 from bf16 Yb -------------------------
  for (int idx = tid; idx < BM * DD; idx += 512) {
    int b = idx >> 9, d = idx & 511;
    unsigned short h = *(const unsigned short*)(Yb + yboff(b, 2 * d));
    out[(size_t)(b0 + b) * 513 + d] = bf2f((unsigned int)h);
  }
}

// ---------------------------------------------------------------------------
// Loss column:  loss = ycum[-2] = 0.01 * sum_{t=1..98} gm_t   (exact algebra)
// ---------------------------------------------------------------------------
__global__ void loss_kernel(const float* __restrict__ bdp,
                            const float* __restrict__ sp,
                            const float* __restrict__ sdp,
                            float* __restrict__ out) {
  int b = blockIdx.x * 256 + threadIdx.x;
  if (b >= NB) return;
  float bd = bdp[b];
  float Kv = sp[b] + __logf(-bd + 0.01f) - __logf(sdp[b] + 0.01f);
  float acc = 0.0f;
  for (int t = 1; t <= 98; ++t) {
    float m = 0.01f * (float)t - 1.0f;     // in (-1, 0)
    float L = __logf(-m);                  // negative
    acc += (-bd) / (m * L) * (Kv - __logf(-L));
  }
  out[(size_t)b * 513 + 512] = 0.01f * acc;
}

// ---------------------------------------------------------------------------
extern "C" void kernel_launch(void* const* d_in, const int* in_sizes, int n_in,
                              void* d_out, int out_size, void* d_ws, size_t ws_size,
                              hipStream_t stream) {
  const float* y0    = (const float*)d_in[0];
  const float* t_seq = (const float*)d_in[1];
  const float* W1    = (const float*)d_in[2];
  const float* b1    = (const float*)d_in[3];
  const float* W2    = (const float*)d_in[4];
  const float* b2    = (const float*)d_in[5];
  const float* W3    = (const float*)d_in[6];
  const float* b3    = (const float*)d_in[7];
  const float* bd    = (const float*)d_in[9];
  const float* s_    = (const float*)d_in[10];
  const float* sd    = (const float*)d_in[11];
  const int*   kptr  = (const int*)d_in[12];
  float* out = (float*)d_out;
  unsigned short* ws = (unsigned short*)d_ws;

  prep_weights<<<576, 256, 0, stream>>>(W1, W2, W3, ws);
  ode_main<<<256, 512, 0, stream>>>(y0, t_seq, b1, b2, b3,
                                    ws, ws + 65536, ws + 81920, kptr, out);
  loss_kernel<<<32, 256, 0, stream>>>(bd, s_, sd, out);
}